// Round 3
// baseline (83.664 us; speedup 1.0000x reference)
//
#include <hip/hip_runtime.h>

#define TSTEPS 32
#define HW 65536   // 256*256
#define NB 32      // batch
#define N_ELEM (NB * HW)        // 2,097,152
#define N4 (N_ELEM / 4)         // 524,288

typedef float vf4 __attribute__((ext_vector_type(4)));

// Order-preserving float<->uint key (works for all floats incl. negatives)
__device__ __forceinline__ unsigned int f2key(float f) {
    unsigned int u = __float_as_uint(f);
    return (u & 0x80000000u) ? ~u : (u | 0x80000000u);
}
__device__ __forceinline__ float key2f(unsigned int k) {
    unsigned int u = (k & 0x80000000u) ? (k & 0x7fffffffu) : ~k;
    return __uint_as_float(u);
}

// ws[0] = min over f2key(x)   (init 0xFFFFFFFF)
// ws[1] = min over ~f2key(x)  (init 0xFFFFFFFF)  -> max key = ~ws[1]
__global__ void lc_minmax(const float4* __restrict__ in, unsigned int* __restrict__ ws) {
    __shared__ unsigned int smin[4], sinvmax[4];
    unsigned int kmin = 0xFFFFFFFFu, kinv = 0xFFFFFFFFu;
    int stride = gridDim.x * blockDim.x;
    for (int i = blockIdx.x * blockDim.x + threadIdx.x; i < N4; i += stride) {
        float4 v = in[i];
        unsigned int k;
        k = f2key(v.x); kmin = min(kmin, k); kinv = min(kinv, ~k);
        k = f2key(v.y); kmin = min(kmin, k); kinv = min(kinv, ~k);
        k = f2key(v.z); kmin = min(kmin, k); kinv = min(kinv, ~k);
        k = f2key(v.w); kmin = min(kmin, k); kinv = min(kinv, ~k);
    }
    // wave64 butterfly reduce
    #pragma unroll
    for (int off = 32; off >= 1; off >>= 1) {
        kmin = min(kmin, (unsigned int)__shfl_xor((int)kmin, off, 64));
        kinv = min(kinv, (unsigned int)__shfl_xor((int)kinv, off, 64));
    }
    int wave = threadIdx.x >> 6;
    if ((threadIdx.x & 63) == 0) { smin[wave] = kmin; sinvmax[wave] = kinv; }
    __syncthreads();
    if (threadIdx.x == 0) {
        #pragma unroll
        for (int w = 1; w < 4; ++w) {
            kmin = min(kmin, smin[w]);
            kinv = min(kinv, sinvmax[w]);
        }
        atomicMin(&ws[0], kmin);
        atomicMin(&ws[1], kinv);
    }
}

__device__ __forceinline__ int spike_t(float x, float mn, float denom, bool valid) {
    // EXACT reference op order: n=(x-mn)/denom ; lat=(1-n)*1.0 ; t=trunc(lat*31)
    float n   = valid ? ((x - mn) / denom) : 0.5f;
    float lat = 1.0f - n;                 // * MAX_LATENCY(=1.0) is exact
    int   t   = (int)(lat * 31.0f);       // lat >= 0 so trunc == floor
    t = t < 0 ? 0 : t;
    t = t > (TSTEPS - 1) ? (TSTEPS - 1) : t;
    return t;
}

__global__ void lc_spike(const float4* __restrict__ in, float* __restrict__ out,
                         const unsigned int* __restrict__ ws) {
    float mn = key2f(ws[0]);
    float mx = key2f(~ws[1]);
    bool  valid = (mx > mn);
    float denom = fmaxf(mx - mn, 1e-12f);

    int idx = blockIdx.x * blockDim.x + threadIdx.x;   // 0 .. N4-1
    if (idx >= N4) return;
    int b   = idx >> 14;          // idx / (HW/4)
    int rem = idx & 16383;        // idx % (HW/4)

    float4 v = in[idx];
    int t0 = spike_t(v.x, mn, denom, valid);
    int t1 = spike_t(v.y, mn, denom, valid);
    int t2 = spike_t(v.z, mn, denom, valid);
    int t3 = spike_t(v.w, mn, denom, valid);

    float* base = out + (size_t)b * TSTEPS * HW + (size_t)rem * 4;
    #pragma unroll
    for (int tt = 0; tt < TSTEPS; ++tt) {
        vf4 o;
        o.x = (tt == t0) ? 1.0f : 0.0f;
        o.y = (tt == t1) ? 1.0f : 0.0f;
        o.z = (tt == t2) ? 1.0f : 0.0f;
        o.w = (tt == t3) ? 1.0f : 0.0f;
        __builtin_nontemporal_store(o, reinterpret_cast<vf4*>(base + (size_t)tt * HW));
    }
}

extern "C" void kernel_launch(void* const* d_in, const int* in_sizes, int n_in,
                              void* d_out, int out_size, void* d_ws, size_t ws_size,
                              hipStream_t stream) {
    const float4*  in = (const float4*)d_in[0];
    float*        out = (float*)d_out;
    unsigned int*  ws = (unsigned int*)d_ws;

    // Both reduction cells (min-key, inverted-max-key) init to 0xFFFFFFFF.
    (void)hipMemsetAsync(ws, 0xFF, 2 * sizeof(unsigned int), stream);
    lc_minmax<<<1024, 256, 0, stream>>>(in, ws);
    lc_spike<<<(N4 + 255) / 256, 256, 0, stream>>>(in, out, ws);
}

// Round 4
// 72.647 us; speedup vs baseline: 1.1517x; 1.1517x over previous
//
#include <hip/hip_runtime.h>

#define TSTEPS 32
#define HW 65536   // 256*256
#define NB 32      // batch
#define N_ELEM (NB * HW)        // 2,097,152
#define N4 (N_ELEM / 4)         // 524,288
#define HW4 (HW / 4)            // 16,384 float4 per plane

// Order-preserving float<->uint key (works for all floats incl. negatives)
__device__ __forceinline__ unsigned int f2key(float f) {
    unsigned int u = __float_as_uint(f);
    return (u & 0x80000000u) ? ~u : (u | 0x80000000u);
}
__device__ __forceinline__ float key2f(unsigned int k) {
    unsigned int u = (k & 0x80000000u) ? (k & 0x7fffffffu) : ~k;
    return __uint_as_float(u);
}

// ws[0] = min over f2key(x)   (init 0xFFFFFFFF)
// ws[1] = min over ~f2key(x)  (init 0xFFFFFFFF)  -> max key = ~ws[1]
__global__ void lc_minmax(const float4* __restrict__ in, unsigned int* __restrict__ ws) {
    __shared__ unsigned int smin[4], sinvmax[4];
    unsigned int kmin = 0xFFFFFFFFu, kinv = 0xFFFFFFFFu;
    int stride = gridDim.x * blockDim.x;
    for (int i = blockIdx.x * blockDim.x + threadIdx.x; i < N4; i += stride) {
        float4 v = in[i];
        unsigned int k;
        k = f2key(v.x); kmin = min(kmin, k); kinv = min(kinv, ~k);
        k = f2key(v.y); kmin = min(kmin, k); kinv = min(kinv, ~k);
        k = f2key(v.z); kmin = min(kmin, k); kinv = min(kinv, ~k);
        k = f2key(v.w); kmin = min(kmin, k); kinv = min(kinv, ~k);
    }
    #pragma unroll
    for (int off = 32; off >= 1; off >>= 1) {
        kmin = min(kmin, (unsigned int)__shfl_xor((int)kmin, off, 64));
        kinv = min(kinv, (unsigned int)__shfl_xor((int)kinv, off, 64));
    }
    int wave = threadIdx.x >> 6;
    if ((threadIdx.x & 63) == 0) { smin[wave] = kmin; sinvmax[wave] = kinv; }
    __syncthreads();
    if (threadIdx.x == 0) {
        #pragma unroll
        for (int w = 1; w < 4; ++w) {
            kmin = min(kmin, smin[w]);
            kinv = min(kinv, sinvmax[w]);
        }
        atomicMin(&ws[0], kmin);
        atomicMin(&ws[1], kinv);
    }
}

__device__ __forceinline__ int spike_t(float x, float mn, float denom, bool valid) {
    // EXACT reference op order: n=(x-mn)/denom ; lat=(1-n)*1.0 ; t=trunc(lat*31)
    float n   = valid ? ((x - mn) / denom) : 0.5f;
    float lat = 1.0f - n;                 // * MAX_LATENCY(=1.0) is exact
    int   t   = (int)(lat * 31.0f);       // lat >= 0 so trunc == floor
    t = t < 0 ? 0 : t;
    t = t > (TSTEPS - 1) ? (TSTEPS - 1) : t;
    return t;
}

// Each block: 256 threads, owns 1024 consecutive float4 (4096 pixels) of ONE
// batch image. Thread handles float4 indices base + tid + j*256, j=0..3.
// Store loop (tt outer, j inner): at each tt the block emits one 16 KB
// contiguous burst -> long DRAM row-buffer hits per time-plane.
__global__ void lc_spike(const float4* __restrict__ in, float* __restrict__ out,
                         const unsigned int* __restrict__ ws) {
    float mn = key2f(ws[0]);
    float mx = key2f(~ws[1]);
    bool  valid = (mx > mn);
    float denom = fmaxf(mx - mn, 1e-12f);

    int bid = blockIdx.x;             // 0 .. 511
    int b   = bid >> 4;               // image index (16 blocks per image)
    int base4 = bid * 1024;           // global float4 index of block start

    float4 v[4];
    int t[4][4];
    #pragma unroll
    for (int j = 0; j < 4; ++j) {
        v[j] = in[base4 + j * 256 + threadIdx.x];
        t[j][0] = spike_t(v[j].x, mn, denom, valid);
        t[j][1] = spike_t(v[j].y, mn, denom, valid);
        t[j][2] = spike_t(v[j].z, mn, denom, valid);
        t[j][3] = spike_t(v[j].w, mn, denom, valid);
    }

    // float4 index within a plane for j=0: block-local offset + tid
    int rem4 = (bid & 15) * 1024 + threadIdx.x;
    float4* outp = reinterpret_cast<float4*>(out) +
                   (size_t)b * TSTEPS * HW4 + rem4;

    #pragma unroll
    for (int tt = 0; tt < TSTEPS; ++tt) {
        #pragma unroll
        for (int j = 0; j < 4; ++j) {
            float4 o;
            o.x = (tt == t[j][0]) ? 1.0f : 0.0f;
            o.y = (tt == t[j][1]) ? 1.0f : 0.0f;
            o.z = (tt == t[j][2]) ? 1.0f : 0.0f;
            o.w = (tt == t[j][3]) ? 1.0f : 0.0f;
            outp[(size_t)tt * HW4 + j * 256] = o;
        }
    }
}

extern "C" void kernel_launch(void* const* d_in, const int* in_sizes, int n_in,
                              void* d_out, int out_size, void* d_ws, size_t ws_size,
                              hipStream_t stream) {
    const float4*  in = (const float4*)d_in[0];
    float*        out = (float*)d_out;
    unsigned int*  ws = (unsigned int*)d_ws;

    // Both reduction cells (min-key, inverted-max-key) init to 0xFFFFFFFF.
    (void)hipMemsetAsync(ws, 0xFF, 2 * sizeof(unsigned int), stream);
    lc_minmax<<<1024, 256, 0, stream>>>(in, ws);
    lc_spike<<<512, 256, 0, stream>>>(in, out, ws);
}

// Round 5
// 47.747 us; speedup vs baseline: 1.7522x; 1.5215x over previous
//
#include <hip/hip_runtime.h>

#define TSTEPS 32
#define HW 65536   // 256*256
#define NB 32      // batch
#define N_ELEM (NB * HW)        // 2,097,152
#define N4 (N_ELEM / 4)         // 524,288
#define RED_BLOCKS 1024         // partial-reduction blocks

// Order-preserving float<->uint key (works for all floats incl. negatives)
__device__ __forceinline__ unsigned int f2key(float f) {
    unsigned int u = __float_as_uint(f);
    return (u & 0x80000000u) ? ~u : (u | 0x80000000u);
}
__device__ __forceinline__ float key2f(unsigned int k) {
    unsigned int u = (k & 0x80000000u) ? (k & 0x7fffffffu) : ~k;
    return __uint_as_float(u);
}

// K1: per-block partial min/inv-max keys -> ws[bid] (min), ws[RED_BLOCKS+bid]
// (inverted max). Pure writes to distinct slots: no init, no atomics,
// deterministic across graph replays.
__global__ void lc_partial(const float4* __restrict__ in, unsigned int* __restrict__ ws) {
    __shared__ unsigned int smin[4], sinv[4];
    int tid = threadIdx.x;
    int i0  = blockIdx.x * 512 + tid;     // two float4 per thread: i0, i0+256
    unsigned int kmin = 0xFFFFFFFFu, kinv = 0xFFFFFFFFu;
    #pragma unroll
    for (int j = 0; j < 2; ++j) {
        float4 v = in[i0 + j * 256];
        unsigned int k;
        k = f2key(v.x); kmin = min(kmin, k); kinv = min(kinv, ~k);
        k = f2key(v.y); kmin = min(kmin, k); kinv = min(kinv, ~k);
        k = f2key(v.z); kmin = min(kmin, k); kinv = min(kinv, ~k);
        k = f2key(v.w); kmin = min(kmin, k); kinv = min(kinv, ~k);
    }
    #pragma unroll
    for (int off = 32; off >= 1; off >>= 1) {
        kmin = min(kmin, (unsigned int)__shfl_xor((int)kmin, off, 64));
        kinv = min(kinv, (unsigned int)__shfl_xor((int)kinv, off, 64));
    }
    int wave = tid >> 6;
    if ((tid & 63) == 0) { smin[wave] = kmin; sinv[wave] = kinv; }
    __syncthreads();
    if (tid == 0) {
        #pragma unroll
        for (int w = 1; w < 4; ++w) {
            kmin = min(kmin, smin[w]);
            kinv = min(kinv, sinv[w]);
        }
        ws[blockIdx.x]              = kmin;
        ws[RED_BLOCKS + blockIdx.x] = kinv;
    }
}

__device__ __forceinline__ int spike_t(float x, float mn, float denom, bool valid) {
    // EXACT reference op order: n=(x-mn)/denom ; lat=(1-n)*1.0 ; t=trunc(lat*31)
    float n   = valid ? ((x - mn) / denom) : 0.5f;
    float lat = 1.0f - n;                 // * MAX_LATENCY(=1.0) is exact
    int   t   = (int)(lat * 31.0f);       // lat >= 0 so trunc == floor
    t = t < 0 ? 0 : t;
    t = t > (TSTEPS - 1) ? (TSTEPS - 1) : t;
    return t;
}

// K2: prologue reduces the 1024 partial pairs (8 KB, L2-hot), then the
// R1-measured spike body: thread = one float4 column, 32 coalesced plane
// stores (64 lanes x 16B = 1KB per instruction).
__global__ void lc_spike(const float4* __restrict__ in, float* __restrict__ out,
                         const unsigned int* __restrict__ ws) {
    __shared__ unsigned int smin[4], sinv[4];
    __shared__ float s_mn, s_mx;
    int tid = threadIdx.x;

    // each thread loads 4 min-keys and 4 inv-keys (256 threads x 4 = 1024)
    uint4 a = reinterpret_cast<const uint4*>(ws)[tid];
    uint4 c = reinterpret_cast<const uint4*>(ws + RED_BLOCKS)[tid];
    unsigned int kmin = min(min(a.x, a.y), min(a.z, a.w));
    unsigned int kinv = min(min(c.x, c.y), min(c.z, c.w));
    #pragma unroll
    for (int off = 32; off >= 1; off >>= 1) {
        kmin = min(kmin, (unsigned int)__shfl_xor((int)kmin, off, 64));
        kinv = min(kinv, (unsigned int)__shfl_xor((int)kinv, off, 64));
    }
    int wave = tid >> 6;
    if ((tid & 63) == 0) { smin[wave] = kmin; sinv[wave] = kinv; }
    __syncthreads();
    if (tid == 0) {
        #pragma unroll
        for (int w = 1; w < 4; ++w) {
            kmin = min(kmin, smin[w]);
            kinv = min(kinv, sinv[w]);
        }
        s_mn = key2f(kmin);
        s_mx = key2f(~kinv);
    }
    __syncthreads();

    float mn = s_mn, mx = s_mx;
    bool  valid = (mx > mn);
    float denom = fmaxf(mx - mn, 1e-12f);

    int idx = blockIdx.x * blockDim.x + tid;   // 0 .. N4-1
    int b   = idx >> 14;          // idx / (HW/4)
    int rem = idx & 16383;        // idx % (HW/4)

    float4 v = in[idx];
    int t0 = spike_t(v.x, mn, denom, valid);
    int t1 = spike_t(v.y, mn, denom, valid);
    int t2 = spike_t(v.z, mn, denom, valid);
    int t3 = spike_t(v.w, mn, denom, valid);

    float* base = out + (size_t)b * TSTEPS * HW + (size_t)rem * 4;
    #pragma unroll
    for (int tt = 0; tt < TSTEPS; ++tt) {
        float4 o;
        o.x = (tt == t0) ? 1.0f : 0.0f;
        o.y = (tt == t1) ? 1.0f : 0.0f;
        o.z = (tt == t2) ? 1.0f : 0.0f;
        o.w = (tt == t3) ? 1.0f : 0.0f;
        *reinterpret_cast<float4*>(base + (size_t)tt * HW) = o;
    }
}

extern "C" void kernel_launch(void* const* d_in, const int* in_sizes, int n_in,
                              void* d_out, int out_size, void* d_ws, size_t ws_size,
                              hipStream_t stream) {
    const float4*  in = (const float4*)d_in[0];
    float*        out = (float*)d_out;
    unsigned int*  ws = (unsigned int*)d_ws;

    lc_partial<<<RED_BLOCKS, 256, 0, stream>>>(in, ws);
    lc_spike<<<N4 / 256, 256, 0, stream>>>(in, out, ws);
}